// Round 1
// baseline (259.224 us; speedup 1.0000x reference)
//
#include <hip/hip_runtime.h>
#include <hip/hip_cooperative_groups.h>

namespace cg = cooperative_groups;

// Problem constants (match reference)
#define NPROP 4096
#define NTOK  16777216
#define BLOCK 1024
#define GRID  512
#define NREP  8
#define STRIDE (GRID * BLOCK)
#define ROUNDS (NTOK / 4 / STRIDE)       // 8 int4 rounds per thread
#define CNT_SHIFT 39
#define SUM_MASK ((1ULL << CNT_SHIFT) - 1)
#define FXP_SCALE 4096.0f                // 2^12 fixed point for losses
#define INV_FXP   (1.0f / 4096.0f)

static_assert(ROUNDS == 8, "pipeline below hardcodes 4+4 rounds");

// ws layout: [0, NREP*NPROP) u64 packed replicas: (count << 39) | fxp_sum
// out layout: out[0]=stratified, out[1]=unweighted, out[2..2+NPROP)=new_freq
//
// Packing budget: per-block cnt <= 32768, fxp <= 32768*5*4096 = 6.7e8 < 2^39.
// Global replica: 64 blocks -> cnt <= 2^21 < 2^25 field, fxp <= 4.3e10 < 2^39. OK.

__device__ __forceinline__ unsigned long long pack_tok(float l) {
    return (1ULL << CNT_SHIFT) | (unsigned long long)(unsigned)(l * FXP_SCALE + 0.5f);
}

// ---------------------------------------------------------------------------
// Fused single-dispatch cooperative kernel:
//   Phase A: zero g_rep (grid-strided) ............. replaces hipMemsetAsync
//   Phase B: LDS histogram w/ 8-deep load pipeline .. replaces hist_kernel
//   Phase C: block 0 finalize ...................... replaces finalize_kernel
// __launch_bounds__(1024, 8): 8 waves/EU min -> VGPR cap 64 -> guarantees the
// 2-blocks/CU co-residency the cooperative launch of 512 blocks requires.
// ---------------------------------------------------------------------------
__global__ __launch_bounds__(BLOCK, 8) void fused_kernel(
    const int* __restrict__ ids, const float* __restrict__ losses,
    const float* __restrict__ prop_freq, const int* __restrict__ d_bc,
    float* __restrict__ out, unsigned long long* __restrict__ g_rep)
{
    cg::grid_group grid = cg::this_grid();
    __shared__ unsigned long long s_hist[NPROP];
    __shared__ float s_red[48];

    // ---- Phase A: zero replicas (32768 u64 across grid) + LDS hist ----
    {
        int g = blockIdx.x * BLOCK + threadIdx.x;
        if (g < NREP * NPROP) g_rep[g] = 0ULL;
    }
    for (int i = threadIdx.x; i < NPROP; i += BLOCK) s_hist[i] = 0ULL;
    grid.sync();

    // ---- Phase B: histogram, 8 loads in flight per wave ----
    const int4*   ids4 = (const int4*)ids;
    const float4* ls4  = (const float4*)losses;
    const int tid = blockIdx.x * BLOCK + threadIdx.x;

    int4   v[4];
    float4 w[4];
#pragma unroll
    for (int b = 0; b < 4; ++b) {          // rounds 0..3 issued, nothing waits yet
        v[b] = ids4[tid + b * STRIDE];
        w[b] = ls4[tid + b * STRIDE];
    }
#pragma unroll
    for (int b = 0; b < 4; ++b) {          // consume round b, refill with round b+4
        int4 id = v[b]; float4 l = w[b];
        v[b] = ids4[tid + (b + 4) * STRIDE];
        w[b] = ls4[tid + (b + 4) * STRIDE];
        atomicAdd(&s_hist[id.x], pack_tok(l.x));
        atomicAdd(&s_hist[id.y], pack_tok(l.y));
        atomicAdd(&s_hist[id.z], pack_tok(l.z));
        atomicAdd(&s_hist[id.w], pack_tok(l.w));
    }
#pragma unroll
    for (int b = 0; b < 4; ++b) {          // drain rounds 4..7
        int4 id = v[b]; float4 l = w[b];
        atomicAdd(&s_hist[id.x], pack_tok(l.x));
        atomicAdd(&s_hist[id.y], pack_tok(l.y));
        atomicAdd(&s_hist[id.z], pack_tok(l.z));
        atomicAdd(&s_hist[id.w], pack_tok(l.w));
    }

    __syncthreads();
    // flush: LDS word is already in replica format — one u64 atomic per bin
    unsigned long long* rep = g_rep + (unsigned)(blockIdx.x & (NREP - 1)) * NPROP;
    for (int i = threadIdx.x; i < NPROP; i += BLOCK) {
        unsigned long long hv = s_hist[i];
        if (hv) atomicAdd(&rep[i], hv);
    }
    grid.sync();

    // ---- Phase C: block 0 finalizes (256 KB of L2-resident reads) ----
    if (blockIdx.x != 0) return;

    const int bc_i = d_bc[0];
    const float bc = (float)bc_i;
    const float ramp = fminf(1.0f, (bc - 1000.0f) / 200.0f);
    const float frac = bc / 3000.0f;

    float a_raw = 0.0f, a_dot = 0.0f, a_tot = 0.0f;

    for (int p = threadIdx.x; p < NPROP; p += BLOCK) {
        unsigned long long vsum = 0;
#pragma unroll
        for (int r = 0; r < NREP; ++r)
            vsum += g_rep[r * NPROP + p];

        float cnt  = (float)(unsigned)(vsum >> CNT_SHIFT);
        float sumf = (float)(vsum & SUM_MASK) * INV_FXP;
        bool present = cnt > 0.0f;
        a_tot += sumf;

        float mean_loss = present ? sumf / fmaxf(cnt, 1.0f) : 0.0f;
        float batch_freq = cnt / ((float)NTOK + 1e-6f);
        float new_freq = prop_freq[p] * 0.99f + (present ? 0.01f * batch_freq : 0.0f);
        out[2 + p] = new_freq;

        float freq_cl = fmaxf(new_freq, 1e-5f);
        float raw = 1.0f / sqrtf(freq_cl + 1e-6f);
        raw = 1.0f + ramp * (raw - 1.0f);
        raw = fminf(30.0f, raw);
        if (bc_i <= 3000) raw = raw * frac + (1.0f - frac);
        if (bc_i <= 1000) raw = 1.0f;

        float wgt = present ? raw : 0.0f;
        a_raw += wgt;
        a_dot += mean_loss * wgt;
    }

    for (int off = 32; off > 0; off >>= 1) {
        a_raw += __shfl_down(a_raw, off, 64);
        a_dot += __shfl_down(a_dot, off, 64);
        a_tot += __shfl_down(a_tot, off, 64);
    }
    int wave = threadIdx.x >> 6;
    if ((threadIdx.x & 63) == 0) {
        s_red[wave]      = a_raw;
        s_red[16 + wave] = a_dot;
        s_red[32 + wave] = a_tot;
    }
    __syncthreads();
    if (threadIdx.x == 0) {
        float t_raw = 0.0f, t_dot = 0.0f, t_tot = 0.0f;
        for (int i = 0; i < 16; ++i) {
            t_raw += s_red[i];
            t_dot += s_red[16 + i];
            t_tot += s_red[32 + i];
        }
        out[0] = t_dot / (t_raw + 1e-6f);   // stratified_loss
        out[1] = t_tot / (float)NTOK;       // unweighted_loss
    }
}

// ---------------------------------------------------------------------------
// Fallback path (previous 3-dispatch version) — used only if the cooperative
// launch is rejected (e.g. occupancy validation failure).
// ---------------------------------------------------------------------------
__global__ __launch_bounds__(BLOCK) void hist_kernel(
    const int* __restrict__ ids, const float* __restrict__ losses,
    unsigned long long* __restrict__ g_rep)
{
    __shared__ unsigned long long s_hist[NPROP];
    for (int i = threadIdx.x; i < NPROP; i += BLOCK) s_hist[i] = 0ULL;
    __syncthreads();

    const int4*   ids4 = (const int4*)ids;
    const float4* ls4  = (const float4*)losses;
    const int tid = blockIdx.x * BLOCK + threadIdx.x;

#pragma unroll 2
    for (int b = 0; b < ROUNDS; ++b) {
        int i = tid + b * STRIDE;
        int4   id = ids4[i];
        float4 l  = ls4[i];
        atomicAdd(&s_hist[id.x], pack_tok(l.x));
        atomicAdd(&s_hist[id.y], pack_tok(l.y));
        atomicAdd(&s_hist[id.z], pack_tok(l.z));
        atomicAdd(&s_hist[id.w], pack_tok(l.w));
    }

    __syncthreads();
    unsigned long long* rep = g_rep + (unsigned)(blockIdx.x & (NREP - 1)) * NPROP;
    for (int i = threadIdx.x; i < NPROP; i += BLOCK) {
        unsigned long long hv = s_hist[i];
        if (hv) atomicAdd(&rep[i], hv);
    }
}

__global__ __launch_bounds__(1024) void finalize_kernel(
    const unsigned long long* __restrict__ g_rep,
    const float* __restrict__ prop_freq, const int* __restrict__ d_bc,
    float* __restrict__ out)
{
    __shared__ float s_raw[16], s_dot[16], s_tot[16];

    const int bc_i = d_bc[0];
    const float bc = (float)bc_i;
    const float ramp = fminf(1.0f, (bc - 1000.0f) / 200.0f);
    const float frac = bc / 3000.0f;

    float a_raw = 0.0f, a_dot = 0.0f, a_tot = 0.0f;

    for (int p = threadIdx.x; p < NPROP; p += 1024) {
        unsigned long long v = 0;
#pragma unroll
        for (int r = 0; r < NREP; ++r)
            v += g_rep[r * NPROP + p];

        float cnt  = (float)(unsigned)(v >> CNT_SHIFT);
        float sumf = (float)(v & SUM_MASK) * INV_FXP;
        bool present = cnt > 0.0f;
        a_tot += sumf;

        float mean_loss = present ? sumf / fmaxf(cnt, 1.0f) : 0.0f;
        float batch_freq = cnt / ((float)NTOK + 1e-6f);
        float new_freq = prop_freq[p] * 0.99f + (present ? 0.01f * batch_freq : 0.0f);
        out[2 + p] = new_freq;

        float freq_cl = fmaxf(new_freq, 1e-5f);
        float raw = 1.0f / sqrtf(freq_cl + 1e-6f);
        raw = 1.0f + ramp * (raw - 1.0f);
        raw = fminf(30.0f, raw);
        if (bc_i <= 3000) raw = raw * frac + (1.0f - frac);
        if (bc_i <= 1000) raw = 1.0f;

        float w = present ? raw : 0.0f;
        a_raw += w;
        a_dot += mean_loss * w;
    }

    for (int off = 32; off > 0; off >>= 1) {
        a_raw += __shfl_down(a_raw, off, 64);
        a_dot += __shfl_down(a_dot, off, 64);
        a_tot += __shfl_down(a_tot, off, 64);
    }
    int wave = threadIdx.x >> 6;
    if ((threadIdx.x & 63) == 0) {
        s_raw[wave] = a_raw;
        s_dot[wave] = a_dot;
        s_tot[wave] = a_tot;
    }
    __syncthreads();
    if (threadIdx.x == 0) {
        float t_raw = 0.0f, t_dot = 0.0f, t_tot = 0.0f;
        for (int i = 0; i < 16; ++i) {
            t_raw += s_raw[i];
            t_dot += s_dot[i];
            t_tot += s_tot[i];
        }
        out[0] = t_dot / (t_raw + 1e-6f);
        out[1] = t_tot / (float)NTOK;
    }
}

extern "C" void kernel_launch(void* const* d_in, const int* in_sizes, int n_in,
                              void* d_out, int out_size, void* d_ws, size_t ws_size,
                              hipStream_t stream) {
    const int*   ids       = (const int*)d_in[0];
    const float* losses    = (const float*)d_in[1];
    const float* prop_freq = (const float*)d_in[2];
    const int*   d_bc      = (const int*)d_in[3];
    float* out = (float*)d_out;

    unsigned long long* g_rep = (unsigned long long*)d_ws;

    void* args[] = { &ids, &losses, &prop_freq, &d_bc, &out, &g_rep };
    hipError_t err = hipLaunchCooperativeKernel((void*)fused_kernel,
                                                dim3(GRID), dim3(BLOCK),
                                                args, 0, stream);
    if (err != hipSuccess) {
        // Fallback: previous verified 3-dispatch path.
        hipMemsetAsync(d_ws, 0, (size_t)NREP * NPROP * 8, stream);
        hist_kernel<<<GRID, BLOCK, 0, stream>>>(ids, losses, g_rep);
        finalize_kernel<<<1, 1024, 0, stream>>>(g_rep, prop_freq, d_bc, out);
    }
}

// Round 2
// 159.867 us; speedup vs baseline: 1.6215x; 1.6215x over previous
//
#include <hip/hip_runtime.h>

// Problem constants (match reference)
#define NPROP 4096
#define NTOK  16777216
#define BLOCK 1024
#define GRID  512
#define NREP  8
#define STRIDE (GRID * BLOCK)
#define ROUNDS (NTOK / 4 / STRIDE)       // 8 int4 rounds per thread
#define CNT_SHIFT 39
#define SUM_MASK ((1ULL << CNT_SHIFT) - 1)
#define FXP_SCALE 4096.0f                // 2^12 fixed point for losses
#define INV_FXP   (1.0f / 4096.0f)

static_assert(ROUNDS == 8, "pipeline below hardcodes 8 rounds");

// ws layout: [0, NREP*NPROP) u64 packed replicas: (count << 39) | fxp_sum
// out layout: out[0]=stratified, out[1]=unweighted, out[2..2+NPROP)=new_freq
//
// Packing budget: per-block cnt <= 32768, fxp <= 32768*5*4096 = 6.7e8 < 2^39.
// Global replica: 64 blocks -> cnt <= 2^21 < 2^25 field, fxp <= 4.3e10 < 2^39. OK.

__device__ __forceinline__ unsigned long long pack_tok(float l) {
    return (1ULL << CNT_SHIFT) | (unsigned long long)(unsigned)(l * FXP_SCALE + 0.5f);
}

#define ATOM4(id, l) do { \
    atomicAdd(&s_hist[(id).x], pack_tok((l).x)); \
    atomicAdd(&s_hist[(id).y], pack_tok((l).y)); \
    atomicAdd(&s_hist[(id).z], pack_tok((l).z)); \
    atomicAdd(&s_hist[(id).w], pack_tok((l).w)); \
} while (0)

// ---------------------------------------------------------------------------
// hist_kernel: LDS u64 histogram with a sched_barrier-PINNED load pipeline.
// Round 1 showed the LLVM scheduler sinks structural prefetches next to their
// consumers (VGPR collapsed to 28, 2 loads in flight, 625 GB/s). The
// __builtin_amdgcn_sched_barrier(0) fences make the 4-round-deep issue order
// non-negotiable: ~10 loads (160 B) in flight per wave, x32 waves/CU.
// __launch_bounds__(1024, 8): VGPR cap 64 -> exactly 2 blocks/CU (LDS 32KB).
// ---------------------------------------------------------------------------
__global__ __launch_bounds__(BLOCK, 8) void hist_kernel(
    const int* __restrict__ ids, const float* __restrict__ losses,
    unsigned long long* __restrict__ g_rep)
{
    __shared__ unsigned long long s_hist[NPROP];
    for (int i = threadIdx.x; i < NPROP; i += BLOCK) s_hist[i] = 0ULL;
    __syncthreads();

    const int4*   ids4 = (const int4*)ids;
    const float4* ls4  = (const float4*)losses;
    const int t = blockIdx.x * BLOCK + threadIdx.x;

    // prologue: rounds 0..3 issued (8 loads in flight), nothing consumed yet
    int4   a0 = ids4[t + 0 * STRIDE], a1 = ids4[t + 1 * STRIDE],
           a2 = ids4[t + 2 * STRIDE], a3 = ids4[t + 3 * STRIDE];
    float4 b0 = ls4[t + 0 * STRIDE],  b1 = ls4[t + 1 * STRIDE],
           b2 = ls4[t + 2 * STRIDE],  b3 = ls4[t + 3 * STRIDE];
    __builtin_amdgcn_sched_barrier(0);

    // steady state: refill round k+4 while consuming round k.
    // Compiler emits counted s_waitcnt vmcnt(N) for the oldest pair only.
    int4 a4 = ids4[t + 4 * STRIDE]; float4 b4 = ls4[t + 4 * STRIDE];
    ATOM4(a0, b0);
    __builtin_amdgcn_sched_barrier(0);
    int4 a5 = ids4[t + 5 * STRIDE]; float4 b5 = ls4[t + 5 * STRIDE];
    ATOM4(a1, b1);
    __builtin_amdgcn_sched_barrier(0);
    int4 a6 = ids4[t + 6 * STRIDE]; float4 b6 = ls4[t + 6 * STRIDE];
    ATOM4(a2, b2);
    __builtin_amdgcn_sched_barrier(0);
    int4 a7 = ids4[t + 7 * STRIDE]; float4 b7 = ls4[t + 7 * STRIDE];
    ATOM4(a3, b3);
    __builtin_amdgcn_sched_barrier(0);

    // drain rounds 4..7
    ATOM4(a4, b4);
    ATOM4(a5, b5);
    ATOM4(a6, b6);
    ATOM4(a7, b7);

    __syncthreads();
    // flush: LDS word is already in replica format — one u64 atomic per bin
    unsigned long long* rep = g_rep + (unsigned)(blockIdx.x & (NREP - 1)) * NPROP;
    for (int i = threadIdx.x; i < NPROP; i += BLOCK) {
        unsigned long long v = s_hist[i];
        if (v) atomicAdd(&rep[i], v);
    }
}

// ---------------------------------------------------------------------------
// finalize_kernel: single block (math order bitwise-identical to the verified
// version -> preserves absmax=0), but all 32 u64 loads per thread are issued
// UP FRONT (pinned) instead of 8-at-a-time: 16 waves x 32 x 8 B = 4 KB in
// flight on the CU, ~3-4x the previous read throughput. Integer r-sums
// commute exactly, so load reordering cannot change any output bit.
// ---------------------------------------------------------------------------
__global__ __launch_bounds__(1024) void finalize_kernel(
    const unsigned long long* __restrict__ g_rep,
    const float* __restrict__ prop_freq, const int* __restrict__ d_bc,
    float* __restrict__ out)
{
    __shared__ float s_raw[16], s_dot[16], s_tot[16];

    const int bc_i = d_bc[0];
    const float bc = (float)bc_i;
    const float ramp = fminf(1.0f, (bc - 1000.0f) / 200.0f);
    const float frac = bc / 3000.0f;

    const int p0 = threadIdx.x;

    // issue ALL 32 independent u64 loads (4 p-slots x 8 replicas), pinned
    unsigned long long v[4][8];
#pragma unroll
    for (int k = 0; k < 4; ++k)
#pragma unroll
        for (int r = 0; r < 8; ++r)
            v[k][r] = g_rep[r * NPROP + p0 + k * 1024];
    // prop_freq for the 4 slots too (independent loads)
    float pf[4];
#pragma unroll
    for (int k = 0; k < 4; ++k) pf[k] = prop_freq[p0 + k * 1024];
    __builtin_amdgcn_sched_barrier(0);

    float a_raw = 0.0f, a_dot = 0.0f, a_tot = 0.0f;

#pragma unroll
    for (int k = 0; k < 4; ++k) {
        const int p = p0 + k * 1024;
        unsigned long long vsum = 0;
#pragma unroll
        for (int r = 0; r < 8; ++r) vsum += v[k][r];

        float cnt  = (float)(unsigned)(vsum >> CNT_SHIFT);
        float sumf = (float)(vsum & SUM_MASK) * INV_FXP;
        bool present = cnt > 0.0f;
        a_tot += sumf;

        float mean_loss = present ? sumf / fmaxf(cnt, 1.0f) : 0.0f;
        float batch_freq = cnt / ((float)NTOK + 1e-6f);
        float new_freq = pf[k] * 0.99f + (present ? 0.01f * batch_freq : 0.0f);
        out[2 + p] = new_freq;

        float freq_cl = fmaxf(new_freq, 1e-5f);
        float raw = 1.0f / sqrtf(freq_cl + 1e-6f);
        raw = 1.0f + ramp * (raw - 1.0f);
        raw = fminf(30.0f, raw);
        if (bc_i <= 3000) raw = raw * frac + (1.0f - frac);
        if (bc_i <= 1000) raw = 1.0f;

        float w = present ? raw : 0.0f;
        a_raw += w;
        a_dot += mean_loss * w;
    }

    for (int off = 32; off > 0; off >>= 1) {
        a_raw += __shfl_down(a_raw, off, 64);
        a_dot += __shfl_down(a_dot, off, 64);
        a_tot += __shfl_down(a_tot, off, 64);
    }
    int wave = threadIdx.x >> 6;
    if ((threadIdx.x & 63) == 0) {
        s_raw[wave] = a_raw;
        s_dot[wave] = a_dot;
        s_tot[wave] = a_tot;
    }
    __syncthreads();
    if (threadIdx.x == 0) {
        float t_raw = 0.0f, t_dot = 0.0f, t_tot = 0.0f;
        for (int i = 0; i < 16; ++i) {
            t_raw += s_raw[i];
            t_dot += s_dot[i];
            t_tot += s_tot[i];
        }
        out[0] = t_dot / (t_raw + 1e-6f);   // stratified_loss
        out[1] = t_tot / (float)NTOK;       // unweighted_loss
    }
}

extern "C" void kernel_launch(void* const* d_in, const int* in_sizes, int n_in,
                              void* d_out, int out_size, void* d_ws, size_t ws_size,
                              hipStream_t stream) {
    const int*   ids       = (const int*)d_in[0];
    const float* losses    = (const float*)d_in[1];
    const float* prop_freq = (const float*)d_in[2];
    const int*   d_bc      = (const int*)d_in[3];
    float* out = (float*)d_out;

    unsigned long long* g_rep = (unsigned long long*)d_ws;

    // zero replicas (ws is re-poisoned to 0xAA before every timed launch)
    hipMemsetAsync(d_ws, 0, (size_t)NREP * NPROP * 8, stream);

    hist_kernel<<<GRID, BLOCK, 0, stream>>>(ids, losses, g_rep);
    finalize_kernel<<<1, 1024, 0, stream>>>(g_rep, prop_freq, d_bc, out);
}